// Round 8
// baseline (398.661 us; speedup 1.0000x reference)
//
#include <hip/hip_runtime.h>
#include <hip/hip_bf16.h>
#include <math.h>

typedef __bf16 bf16;
typedef __attribute__((ext_vector_type(8))) __bf16 bf16x8;
typedef __attribute__((ext_vector_type(4))) __bf16 bf16x4;
typedef __attribute__((ext_vector_type(4))) float f32x4;

#define MFMA16(a,b,c) __builtin_amdgcn_mfma_f32_16x16x32_bf16(a,b,c,0,0,0)

// Problem constants
#define BATCH 2
#define SEQ   2048
#define DMODEL 768
#define NH    12
#define NKV   4
#define NREP  3
#define HD    64
#define FFDIM 2048
#define ROWS  (BATCH*SEQ)   // 4096

#define QSCALE 0.18033688011112042f
#define LOG2E  1.4426950408889634f

__device__ __forceinline__ void gl2lds16(const bf16* g, bf16* l) {
  __builtin_amdgcn_global_load_lds(
      (const __attribute__((address_space(1))) void*)g,
      (__attribute__((address_space(3))) void*)l, 16, 0, 0);
}

__device__ __forceinline__ bf16x8 pack8(f32x4 a, f32x4 b) {
  bf16x8 o;
  o[0] = (bf16)a[0]; o[1] = (bf16)a[1]; o[2] = (bf16)a[2]; o[3] = (bf16)a[3];
  o[4] = (bf16)b[0]; o[5] = (bf16)b[1]; o[6] = (bf16)b[2]; o[7] = (bf16)b[3];
  return o;
}

// ---------------- RoPE cos/sin table ----------------
__global__ __launch_bounds__(256) void rope_tab_kernel(float* __restrict__ tab) {
  int id = blockIdx.x * 256 + threadIdx.x;    // 65536 = 32 j * 2048 s
  int j = id >> 11, s = id & 2047;
  float inv = expf(-(float)j * (9.210340371976184f / 32.0f));
  float ang = (float)s * inv;
  tab[id] = cosf(ang);
  tab[65536 + id] = sinf(ang);
}

// ---------------- RMSNorm (vectorized f32x4, 192 threads) ----------------
__global__ __launch_bounds__(192) void rmsnorm_kernel(const float* __restrict__ x,
    const float* __restrict__ g, bf16* __restrict__ out) {
  int row = blockIdx.x;
  const float* xr = x + (size_t)row * DMODEL;
  int t = threadIdx.x;
  f32x4 v = *(const f32x4*)(xr + t * 4);
  float ss = v[0] * v[0] + v[1] * v[1] + v[2] * v[2] + v[3] * v[3];
  #pragma unroll
  for (int off = 32; off; off >>= 1) ss += __shfl_xor(ss, off, 64);
  __shared__ float red[3];
  if ((t & 63) == 0) red[t >> 6] = ss;
  __syncthreads();
  float total = red[0] + red[1] + red[2];
  float norm = sqrtf(total) * 0.03608439182435161f;  // 768^-0.5
  float sc = 1.0f / (norm + 1e-6f);
  f32x4 gv = *(const f32x4*)(g + t * 4);
  bf16x4 o;
  #pragma unroll
  for (int i = 0; i < 4; ++i) o[i] = (bf16)(gv[i] * v[i] * sc);
  *(bf16x4*)(out + (size_t)row * DMODEL + t * 4) = o;
}

// ---------------- Barrier-free per-wave register GEMM: C = A@B^T + R (fp32 out) ----------
// Block = 4 independent waves stacked by rows (no LDS, no __syncthreads).
// Wave tile 32x64: acc[2][4]. A bf16 direct frag loads; B fp32 -> in-register pack.
// Explicit 2-stage pipeline: stage loads issued a full outer iteration before use.
struct BStage { f32x4 v[8]; };

__device__ __forceinline__ void loadB(const float* Bbase, int k, BStage& s, int K) {
  #pragma unroll
  for (int n = 0; n < 4; ++n) {
    const float* p = Bbase + (size_t)(n * 16) * K + k;
    s.v[n * 2]     = *(const f32x4*)(p);
    s.v[n * 2 + 1] = *(const f32x4*)(p + 4);
  }
}

__device__ __forceinline__ void loadA(const bf16* Abase, int k, bf16x8& a0, bf16x8& a1, int K) {
  a0 = *(const bf16x8*)(Abase + k);
  a1 = *(const bf16x8*)(Abase + (size_t)16 * K + k);
}

__device__ __forceinline__ void gstep(f32x4 acc[2][4], bf16x8 a0, bf16x8 a1, const BStage& s) {
  #pragma unroll
  for (int n = 0; n < 4; ++n) {
    bf16x8 bb = pack8(s.v[2 * n], s.v[2 * n + 1]);
    acc[0][n] = MFMA16(a0, bb, acc[0][n]);
    acc[1][n] = MFMA16(a1, bb, acc[1][n]);
  }
}

__global__ __launch_bounds__(256) void gemm_reg_kernel(const bf16* __restrict__ A,
    const float* __restrict__ Bf, float* __restrict__ C, const float* __restrict__ R,
    int N, int K) {
  int t = threadIdx.x;
  int lane = t & 63, wave = t >> 6;
  int l15 = lane & 15, lq = lane >> 4;
  int row0 = blockIdx.y * 128 + wave * 32;
  int col0 = blockIdx.x * 64;
  const bf16* Abase = A + (size_t)(row0 + l15) * K + lq * 8;
  const float* Bbase = Bf + (size_t)(col0 + l15) * K + lq * 8;

  f32x4 zero = {0.f, 0.f, 0.f, 0.f};
  f32x4 acc[2][4];
  #pragma unroll
  for (int m = 0; m < 2; ++m)
    #pragma unroll
    for (int n = 0; n < 4; ++n) acc[m][n] = zero;

  bf16x8 a0A, a1A, a0B, a1B;
  BStage bA, bB;
  loadA(Abase, 0, a0A, a1A, K);  loadB(Bbase, 0, bA, K);
  loadA(Abase, 32, a0B, a1B, K); loadB(Bbase, 32, bB, K);

  for (int k0 = 0; k0 < K; k0 += 64) {
    int kA = (k0 + 64 < K) ? k0 + 64 : 0;   // clamped dummy reload on last iter
    int kB = (k0 + 96 < K) ? k0 + 96 : 0;
    gstep(acc, a0A, a1A, bA);
    loadA(Abase, kA, a0A, a1A, K); loadB(Bbase, kA, bA, K);
    gstep(acc, a0B, a1B, bB);
    loadA(Abase, kB, a0B, a1B, K); loadB(Bbase, kB, bB, K);
  }

  #pragma unroll
  for (int m = 0; m < 2; ++m)
    #pragma unroll
    for (int n = 0; n < 4; ++n)
      #pragma unroll
      for (int r = 0; r < 4; ++r) {
        size_t idx = (size_t)(row0 + m * 16 + lq * 4 + r) * N + (col0 + n * 16 + l15);
        C[idx] = acc[m][n][r] + R[idx];
      }
}

// ---------------- QKV GEMM (fp32 W) + fused RoPE epilogue -> Qh/Kh/Vt ----------
__global__ __launch_bounds__(256) void gemm_qkv_kernel(const bf16* __restrict__ A,
    const float* __restrict__ Wq, const float* __restrict__ Wk, const float* __restrict__ Wv,
    const float* __restrict__ tab, bf16* __restrict__ Qh, bf16* __restrict__ Kh,
    bf16* __restrict__ Vt) {
  __shared__ __align__(16) bf16 At[64 * 32];
  __shared__ __align__(16) bf16 Bt[128 * 32];
  const int K = DMODEL;
  int t = threadIdx.x;
  int lane = t & 63, wave = t >> 6;
  int l15 = lane & 15, lq = lane >> 4;
  int wrow = (wave >> 1) * 32, wcol = (wave & 1) * 64;
  int row0 = blockIdx.y * 64;
  int col0 = blockIdx.x * 128;
  int srow = t >> 2, sseg = (t & 3) * 8;

  const float* Bsrc; int brow;
  if (col0 < 768)       { Bsrc = Wq; brow = col0; }
  else if (col0 < 1024) { Bsrc = Wk; brow = col0 - 768; }
  else                  { Bsrc = Wv; brow = col0 - 1024; }

  const bf16* Ag0 = A + (size_t)(row0 + srow) * K + sseg;
  const float* Bg0 = Bsrc + (size_t)(brow + srow) * K + sseg;
  const float* Bg1 = Bg0 + (size_t)64 * K;
  bf16* Al0 = At + t * 8;
  bf16* Bl0 = Bt + t * 8;
  bf16* Bl1 = Bt + 2048 + t * 8;

  f32x4 b0a = *(const f32x4*)(Bg0), b0b = *(const f32x4*)(Bg0 + 4);
  f32x4 b1a = *(const f32x4*)(Bg1), b1b = *(const f32x4*)(Bg1 + 4);

  f32x4 zero = {0.f, 0.f, 0.f, 0.f};
  f32x4 acc[2][4];
  #pragma unroll
  for (int m = 0; m < 2; ++m)
    #pragma unroll
    for (int n = 0; n < 4; ++n) acc[m][n] = zero;

  for (int k0 = 0; k0 < K; k0 += 32) {
    __syncthreads();
    gl2lds16(Ag0 + k0, Al0);
    *(bf16x8*)Bl0 = pack8(b0a, b0b);
    *(bf16x8*)Bl1 = pack8(b1a, b1b);
    if (k0 + 32 < K) {
      b0a = *(const f32x4*)(Bg0 + k0 + 32); b0b = *(const f32x4*)(Bg0 + k0 + 36);
      b1a = *(const f32x4*)(Bg1 + k0 + 32); b1b = *(const f32x4*)(Bg1 + k0 + 36);
    }
    __syncthreads();
    bf16x8 af[2], bfr[4];
    #pragma unroll
    for (int m = 0; m < 2; ++m)
      af[m] = *(const bf16x8*)(At + (wrow + m * 16 + l15) * 32 + lq * 8);
    #pragma unroll
    for (int n = 0; n < 4; ++n)
      bfr[n] = *(const bf16x8*)(Bt + (wcol + n * 16 + l15) * 32 + lq * 8);
    #pragma unroll
    for (int m = 0; m < 2; ++m)
      #pragma unroll
      for (int n = 0; n < 4; ++n)
        acc[m][n] = MFMA16(af[m], bfr[n], acc[m][n]);
  }

  // ---- epilogue: RoPE (Q,K) / transpose-store (V) ----
  int b = row0 >> 11;
  int s0 = (row0 & 2047) + wrow + lq * 4;
  int colw = col0 + wcol;
  if (colw < 768) {
    int h = colw >> 6;
    f32x4 cv[2][2], sv[2][2];
    #pragma unroll
    for (int m = 0; m < 2; ++m)
      #pragma unroll
      for (int jh = 0; jh < 2; ++jh) {
        const float* cp = tab + (jh * 16 + l15) * 2048 + s0 + m * 16;
        cv[m][jh] = *(const f32x4*)cp;
        sv[m][jh] = *(const f32x4*)(cp + 65536);
      }
    #pragma unroll
    for (int m = 0; m < 2; ++m)
      #pragma unroll
      for (int n = 0; n < 4; ++n) {
        float sgn = (n < 2) ? -1.f : 1.f;
        #pragma unroll
        for (int r = 0; r < 4; ++r) {
          float c = cv[m][n & 1][r], si = sv[m][n & 1][r];
          float rp = (acc[m][n][r] * c + sgn * acc[m][n ^ 2][r] * si) * QSCALE;
          Qh[((size_t)(b * NH + h) * SEQ + s0 + m * 16 + r) * 64 + n * 16 + l15] = (bf16)rp;
        }
      }
  } else if (colw < 1024) {
    int kh = (colw - 768) >> 6;
    f32x4 cv[2][2], sv[2][2];
    #pragma unroll
    for (int m = 0; m < 2; ++m)
      #pragma unroll
      for (int jh = 0; jh < 2; ++jh) {
        const float* cp = tab + (jh * 16 + l15) * 2048 + s0 + m * 16;
        cv[m][jh] = *(const f32x4*)cp;
        sv[m][jh] = *(const f32x4*)(cp + 65536);
      }
    #pragma unroll
    for (int m = 0; m < 2; ++m)
      #pragma unroll
      for (int n = 0; n < 4; ++n) {
        float sgn = (n < 2) ? -1.f : 1.f;
        #pragma unroll
        for (int r = 0; r < 4; ++r) {
          float c = cv[m][n & 1][r], si = sv[m][n & 1][r];
          float rp = acc[m][n][r] * c + sgn * acc[m][n ^ 2][r] * si;
          Kh[((size_t)(b * NKV + kh) * SEQ + s0 + m * 16 + r) * 64 + n * 16 + l15] = (bf16)rp;
        }
      }
  } else {
    int vh = (colw - 1024) >> 6;
    #pragma unroll
    for (int m = 0; m < 2; ++m)
      #pragma unroll
      for (int n = 0; n < 4; ++n) {
        bf16x4 pv;
        #pragma unroll
        for (int r = 0; r < 4; ++r) pv[r] = (bf16)acc[m][n][r];
        *(bf16x4*)(Vt + ((size_t)(b * NKV + vh) * 64 + n * 16 + l15) * SEQ + s0 + m * 16) = pv;
      }
  }
}

// ---------------- Fused gate/up GEMM (fp32 W) + silu ----------
__global__ __launch_bounds__(256) void gemm_gu_kernel(const bf16* __restrict__ A,
    const float* __restrict__ Wg, const float* __restrict__ Wu, bf16* __restrict__ H) {
  __shared__ __align__(16) bf16 At[128 * 32];
  __shared__ __align__(16) bf16 Bgt[64 * 32];
  __shared__ __align__(16) bf16 But[64 * 32];
  const int K = DMODEL;
  int t = threadIdx.x;
  int lane = t & 63, wave = t >> 6;
  int l15 = lane & 15, lq = lane >> 4;
  int wrow = (wave >> 1) * 64, wcol = (wave & 1) * 32;
  int row0 = blockIdx.y * 128;
  int col0 = blockIdx.x * 64;
  int srow = t >> 2, sseg = (t & 3) * 8;
  const bf16* Ag0 = A + (size_t)(row0 + srow) * K + sseg;
  const bf16* Ag1 = Ag0 + (size_t)64 * K;
  const float* Gg = Wg + (size_t)(col0 + srow) * K + sseg;
  const float* Ug = Wu + (size_t)(col0 + srow) * K + sseg;
  bf16* Al0 = At + t * 8;
  bf16* Al1 = At + 2048 + t * 8;
  bf16* Bgd = Bgt + t * 8;
  bf16* Bud = But + t * 8;

  f32x4 ga = *(const f32x4*)(Gg), gb = *(const f32x4*)(Gg + 4);
  f32x4 ua = *(const f32x4*)(Ug), ub = *(const f32x4*)(Ug + 4);

  f32x4 zero = {0.f, 0.f, 0.f, 0.f};
  f32x4 ag[4][2], au[4][2];
  #pragma unroll
  for (int m = 0; m < 4; ++m)
    #pragma unroll
    for (int n = 0; n < 2; ++n) { ag[m][n] = zero; au[m][n] = zero; }

  for (int k0 = 0; k0 < K; k0 += 32) {
    __syncthreads();
    gl2lds16(Ag0 + k0, Al0);
    gl2lds16(Ag1 + k0, Al1);
    *(bf16x8*)Bgd = pack8(ga, gb);
    *(bf16x8*)Bud = pack8(ua, ub);
    if (k0 + 32 < K) {
      ga = *(const f32x4*)(Gg + k0 + 32); gb = *(const f32x4*)(Gg + k0 + 36);
      ua = *(const f32x4*)(Ug + k0 + 32); ub = *(const f32x4*)(Ug + k0 + 36);
    }
    __syncthreads();
    bf16x8 af[4], bg[2], bu[2];
    #pragma unroll
    for (int m = 0; m < 4; ++m)
      af[m] = *(const bf16x8*)(At + (wrow + m * 16 + l15) * 32 + lq * 8);
    #pragma unroll
    for (int n = 0; n < 2; ++n) {
      bg[n] = *(const bf16x8*)(Bgt + (wcol + n * 16 + l15) * 32 + lq * 8);
      bu[n] = *(const bf16x8*)(But + (wcol + n * 16 + l15) * 32 + lq * 8);
    }
    #pragma unroll
    for (int m = 0; m < 4; ++m)
      #pragma unroll
      for (int n = 0; n < 2; ++n) {
        ag[m][n] = MFMA16(af[m], bg[n], ag[m][n]);
        au[m][n] = MFMA16(af[m], bu[n], au[m][n]);
      }
  }
  #pragma unroll
  for (int m = 0; m < 4; ++m)
    #pragma unroll
    for (int n = 0; n < 2; ++n)
      #pragma unroll
      for (int r = 0; r < 4; ++r) {
        int row = row0 + wrow + m * 16 + lq * 4 + r;
        int col = col0 + wcol + n * 16 + l15;
        float g = ag[m][n][r], u = au[m][n][r];
        float sg = g / (1.f + __builtin_amdgcn_exp2f(-g * LOG2E));
        H[(size_t)row * FFDIM + col] = (bf16)(sg * u);
      }
}

// ---------------- Flash attention: S-transpose + fixed-max softmax ----------
__global__ __launch_bounds__(256) void attn_kernel(const bf16* __restrict__ Qh,
    const bf16* __restrict__ Kh, const bf16* __restrict__ Vt, bf16* __restrict__ out) {
  __shared__ __align__(16) bf16 Kl0[64 * 32];
  __shared__ __align__(16) bf16 Kl1[64 * 32];
  __shared__ __align__(16) bf16 Vl0[64 * 32];
  __shared__ __align__(16) bf16 Vl1[64 * 32];
  __shared__ __align__(16) bf16 P[4][16 * 80];

  int idx = blockIdx.x;
  int qt = 31 - (idx / 24);
  int bh = idx % 24;
  int q0blk = qt * 64;
  int b = bh / NH, h = bh % NH;
  int kvh = h / NREP;
  int t = threadIdx.x;
  int lane = t & 63, wave = t >> 6;
  int l15 = lane & 15, lq = lane >> 4;
  int qw = q0blk + wave * 16;
  const bf16* Qb = Qh + (size_t)(b * NH + h) * SEQ * 64;
  const bf16* Kb = Kh + (size_t)(b * NKV + kvh) * SEQ * 64;
  const bf16* Vb = Vt + (size_t)(b * NKV + kvh) * 64 * SEQ;

  bf16x8 bq0 = *(const bf16x8*)(Qb + (size_t)(qw + l15) * 64 + lq * 8);
  bf16x8 bq1 = *(const bf16x8*)(Qb + (size_t)(qw + l15) * 64 + 32 + lq * 8);

  const bf16* Kg = Kb + (size_t)(t >> 2) * 64 + (t & 3) * 8;
  const bf16* Vg = Vb + (size_t)(t >> 2) * SEQ + (t & 3) * 8;
  bf16* Kl0d = Kl0 + t * 8;
  bf16* Kl1d = Kl1 + t * 8;
  bf16* Vl0d = Vl0 + t * 8;
  bf16* Vl1d = Vl1 + t * 8;
  bf16* Pw = P[wave];
  int Pwq = l15 * 80, lq8 = lq * 8, lq4 = lq * 4;

  f32x4 zero = {0.f, 0.f, 0.f, 0.f};
  f32x4 o[4];
  o[0] = zero; o[1] = zero; o[2] = zero; o[3] = zero;
  float l_r = 0.f;

  for (int k0 = 0; k0 <= q0blk + 63; k0 += 64) {
    __syncthreads();
    gl2lds16(Kg + (size_t)k0 * 64, Kl0d);
    gl2lds16(Kg + (size_t)k0 * 64 + 32, Kl1d);
    gl2lds16(Vg + k0, Vl0d);
    gl2lds16(Vg + k0 + 32, Vl1d);
    __syncthreads();
    f32x4 s[4];
    #pragma unroll
    for (int c = 0; c < 4; ++c) {
      bf16x8 ak0 = *(const bf16x8*)(Kl0 + (c * 16 + l15) * 32 + lq8);
      bf16x8 ak1 = *(const bf16x8*)(Kl1 + (c * 16 + l15) * 32 + lq8);
      s[c] = zero;
      s[c] = MFMA16(ak0, bq0, s[c]);
      s[c] = MFMA16(ak1, bq1, s[c]);
    }
    if (k0 + 63 > qw) {
      int qmk = qw + l15 - k0 - lq4;
      #pragma unroll
      for (int c = 0; c < 4; ++c)
        #pragma unroll
        for (int r = 0; r < 4; ++r)
          if (c * 16 + r > qmk) s[c][r] = -INFINITY;
    }
    #pragma unroll
    for (int c = 0; c < 4; ++c) {
      bf16x4 pe;
      #pragma unroll
      for (int r = 0; r < 4; ++r) {
        float e = __builtin_amdgcn_exp2f(s[c][r]);
        l_r += e;
        pe[r] = (bf16)e;
      }
      *(bf16x4*)(Pw + Pwq + c * 16 + lq4) = pe;
    }
    bf16x8 bp0 = *(const bf16x8*)(Pw + Pwq + lq8);
    bf16x8 bp1 = *(const bf16x8*)(Pw + Pwq + 32 + lq8);
    #pragma unroll
    for (int n = 0; n < 4; ++n) {
      bf16x8 av0 = *(const bf16x8*)(Vl0 + (n * 16 + l15) * 32 + lq8);
      bf16x8 av1 = *(const bf16x8*)(Vl1 + (n * 16 + l15) * 32 + lq8);
      o[n] = MFMA16(av0, bp0, o[n]);
      o[n] = MFMA16(av1, bp1, o[n]);
    }
  }
  float lt = l_r;
  lt += __shfl_xor(lt, 16, 64);
  lt += __shfl_xor(lt, 32, 64);
  float inv = 1.f / lt;
  int q = qw + l15;
  bf16* orow = out + (size_t)(b * SEQ + q) * DMODEL + h * 64;
  #pragma unroll
  for (int n = 0; n < 4; ++n) {
    bf16x4 po;
    #pragma unroll
    for (int r = 0; r < 4; ++r) po[r] = (bf16)(o[n][r] * inv);
    *(bf16x4*)(orow + n * 16 + lq4) = po;
  }
}

extern "C" void kernel_launch(void* const* d_in, const int* in_sizes, int n_in,
                              void* d_out, int out_size, void* d_ws, size_t ws_size,
                              hipStream_t stream) {
  const float* x     = (const float*)d_in[0];
  const float* Wq    = (const float*)d_in[1];
  const float* Wk    = (const float*)d_in[2];
  const float* Wv    = (const float*)d_in[3];
  const float* Wo    = (const float*)d_in[4];
  const float* Wgate = (const float*)d_in[5];
  const float* Wup   = (const float*)d_in[6];
  const float* Wdown = (const float*)d_in[7];
  const float* g1    = (const float*)d_in[8];
  const float* g2    = (const float*)d_in[9];
  float* out = (float*)d_out;

  char* ws = (char*)d_ws;
  size_t off = 0;
  auto alloc = [&](size_t bytes) { size_t o = off; off += (bytes + 255) & ~(size_t)255; return o; };
  size_t o_tab = alloc((size_t)2 * 32 * 2048 * 4);          // 512KB cos/sin
  size_t o_x1  = alloc((size_t)4096 * 768 * 4);
  size_t o_xn  = alloc((size_t)4096 * 768 * 2);
  size_t o_Qh  = alloc((size_t)2 * 12 * 2048 * 64 * 2);
  size_t o_Kh  = alloc((size_t)2 * 4 * 2048 * 64 * 2);
  size_t o_Vt  = alloc((size_t)2 * 4 * 64 * 2048 * 2);
  size_t o_ao  = alloc((size_t)4096 * 768 * 2);
  size_t o_H   = alloc((size_t)4096 * 2048 * 2);
  if (ws_size < off) return;

  float* tab  = (float*)(ws + o_tab);
  float* fx1  = (float*)(ws + o_x1);
  bf16* bxn   = (bf16*)(ws + o_xn);
  bf16* bQh   = (bf16*)(ws + o_Qh);
  bf16* bKh   = (bf16*)(ws + o_Kh);
  bf16* bVt   = (bf16*)(ws + o_Vt);
  bf16* bao   = (bf16*)(ws + o_ao);
  bf16* bH    = (bf16*)(ws + o_H);

  rope_tab_kernel<<<256, 256, 0, stream>>>(tab);

  // Attention sublayer
  rmsnorm_kernel<<<4096, 192, 0, stream>>>(x, g1, bxn);
  gemm_qkv_kernel<<<dim3(10, 64), 256, 0, stream>>>(bxn, Wq, Wk, Wv, tab, bQh, bKh, bVt);
  attn_kernel<<<dim3(768), 256, 0, stream>>>(bQh, bKh, bVt, bao);
  gemm_reg_kernel<<<dim3(12, 32), 256, 0, stream>>>(bao, Wo, fx1, x, 768, 768);

  // FFN sublayer
  rmsnorm_kernel<<<4096, 192, 0, stream>>>(fx1, g2, bxn);
  gemm_gu_kernel<<<dim3(32, 32), 256, 0, stream>>>(bxn, Wgate, Wup, bH);
  gemm_reg_kernel<<<dim3(12, 32), 256, 0, stream>>>(bH, Wdown, out, fx1, 768, 2048);
}

// Round 9
// 260.999 us; speedup vs baseline: 1.5274x; 1.5274x over previous
//
#include <hip/hip_runtime.h>
#include <hip/hip_bf16.h>
#include <math.h>

typedef __bf16 bf16;
typedef __attribute__((ext_vector_type(8))) __bf16 bf16x8;
typedef __attribute__((ext_vector_type(4))) __bf16 bf16x4;
typedef __attribute__((ext_vector_type(4))) float f32x4;

#define MFMA16(a,b,c) __builtin_amdgcn_mfma_f32_16x16x32_bf16(a,b,c,0,0,0)

// Problem constants
#define BATCH 2
#define SEQ   2048
#define DMODEL 768
#define NH    12
#define NKV   4
#define NREP  3
#define HD    64
#define FFDIM 2048
#define ROWS  (BATCH*SEQ)   // 4096

#define QSCALE 0.18033688011112042f
#define LOG2E  1.4426950408889634f

// Partial-drain barrier: wait until <=N vector-mem ops outstanding, then barrier.
// This is the AITER/hipBLASLt pattern — prefetched gl2lds stages stay in flight
// across the barrier (a plain __syncthreads would emit vmcnt(0) and drain them).
#define WB(N) asm volatile("s_waitcnt vmcnt(" #N ")\n\ts_barrier" ::: "memory")
#define BAR() asm volatile("s_barrier" ::: "memory")

__device__ __forceinline__ void gl2lds16(const bf16* g, bf16* l) {
  __builtin_amdgcn_global_load_lds(
      (const __attribute__((address_space(1))) void*)g,
      (__attribute__((address_space(3))) void*)l, 16, 0, 0);
}

// ---------------- fused fp32 -> bf16 convert (7 weight segments) ----------------
struct Cvt7 { const float* s[7]; bf16* d[7]; int n[7]; };
__global__ __launch_bounds__(256) void cvt_all_kernel(Cvt7 c) {
  int seg = blockIdx.y;
  const float* __restrict__ src = c.s[seg];
  bf16* __restrict__ dst = c.d[seg];
  int n = c.n[seg];
  int stride = gridDim.x * 256;
  for (int i = blockIdx.x * 256 + threadIdx.x; i < n; i += stride)
    dst[i] = (bf16)src[i];
}

// ---------------- RoPE cos/sin table ----------------
__global__ __launch_bounds__(256) void rope_tab_kernel(float* __restrict__ tab) {
  int id = blockIdx.x * 256 + threadIdx.x;    // 65536 = 32 j * 2048 s
  int j = id >> 11, s = id & 2047;
  float inv = expf(-(float)j * (9.210340371976184f / 32.0f));
  float ang = (float)s * inv;
  tab[id] = cosf(ang);
  tab[65536 + id] = sinf(ang);
}

// ---------------- RMSNorm (vectorized f32x4, 192 threads) ----------------
__global__ __launch_bounds__(192) void rmsnorm_kernel(const float* __restrict__ x,
    const float* __restrict__ g, bf16* __restrict__ out) {
  int row = blockIdx.x;
  const float* xr = x + (size_t)row * DMODEL;
  int t = threadIdx.x;
  f32x4 v = *(const f32x4*)(xr + t * 4);
  float ss = v[0] * v[0] + v[1] * v[1] + v[2] * v[2] + v[3] * v[3];
  #pragma unroll
  for (int off = 32; off; off >>= 1) ss += __shfl_xor(ss, off, 64);
  __shared__ float red[3];
  if ((t & 63) == 0) red[t >> 6] = ss;
  __syncthreads();
  float total = red[0] + red[1] + red[2];
  float norm = sqrtf(total) * 0.03608439182435161f;  // 768^-0.5
  float sc = 1.0f / (norm + 1e-6f);
  f32x4 gv = *(const f32x4*)(g + t * 4);
  bf16x4 o;
  #pragma unroll
  for (int i = 0; i < 4; ++i) o[i] = (bf16)(gv[i] * v[i] * sc);
  *(bf16x4*)(out + (size_t)row * DMODEL + t * 4) = o;
}

// ---------------- Deep-pipelined GEMM 64x128: C(fp32) = A@B^T + R ----------------
// 4-slot LDS ring, prefetch distance 3 (L=3 loads/thread/stage, wait vmcnt(9)).
__global__ __launch_bounds__(256) void gemm_pipe_kernel(const bf16* __restrict__ A,
    const bf16* __restrict__ B, float* __restrict__ C, const float* __restrict__ R,
    int N, int K) {
  __shared__ __align__(16) bf16 At[4][64 * 32];    // 16KB
  __shared__ __align__(16) bf16 Bt[4][128 * 32];   // 32KB
  int t = threadIdx.x, lane = t & 63, wave = t >> 6;
  int l15 = lane & 15, lq = lane >> 4;
  int wrow = (wave >> 1) * 32, wcol = (wave & 1) * 64;
  int row0 = blockIdx.y * 64, col0 = blockIdx.x * 128;
  const bf16* Ag  = A + (size_t)(row0 + (t >> 2)) * K + (t & 3) * 8;
  const bf16* Bg0 = B + (size_t)(col0 + (t >> 2)) * K + (t & 3) * 8;
  const bf16* Bg1 = Bg0 + (size_t)64 * K;
  const int NS = K / 32;

  #pragma unroll
  for (int s = 0; s < 4; ++s) {
    int ks = (s < NS ? s : NS - 1) * 32;
    gl2lds16(Ag + ks,  At[s] + t * 8);
    gl2lds16(Bg0 + ks, Bt[s] + t * 8);
    gl2lds16(Bg1 + ks, Bt[s] + 2048 + t * 8);
  }

  f32x4 zero = {0.f, 0.f, 0.f, 0.f};
  f32x4 acc[2][4];
  #pragma unroll
  for (int m = 0; m < 2; ++m)
    #pragma unroll
    for (int n = 0; n < 4; ++n) acc[m][n] = zero;

  #define GP_COMPUTE(slot) do {                                              \
    const bf16* at = At[slot]; const bf16* bt = Bt[slot];                    \
    bf16x8 af[2], bfr[4];                                                    \
    _Pragma("unroll")                                                        \
    for (int m = 0; m < 2; ++m)                                              \
      af[m] = *(const bf16x8*)(at + (wrow + m * 16 + l15) * 32 + lq * 8);    \
    _Pragma("unroll")                                                        \
    for (int n = 0; n < 4; ++n)                                              \
      bfr[n] = *(const bf16x8*)(bt + (wcol + n * 16 + l15) * 32 + lq * 8);   \
    _Pragma("unroll")                                                        \
    for (int m = 0; m < 2; ++m)                                              \
      _Pragma("unroll")                                                      \
      for (int n = 0; n < 4; ++n)                                            \
        acc[m][n] = MFMA16(af[m], bfr[n], acc[m][n]);                        \
  } while (0)

  for (int k = 0; k < NS - 3; ++k) {
    WB(9);                        // stage k resident for all waves
    GP_COMPUTE(k & 3);
    BAR();                        // all waves done reading slot k&3
    if (k <= NS - 5) {
      int ks = (k + 4) * 32;
      gl2lds16(Ag + ks,  At[k & 3] + t * 8);
      gl2lds16(Bg0 + ks, Bt[k & 3] + t * 8);
      gl2lds16(Bg1 + ks, Bt[k & 3] + 2048 + t * 8);
    }
  }
  for (int k = (NS - 3 > 0 ? NS - 3 : 0); k < NS; ++k) {
    WB(0);                        // conservative tail drain (once)
    GP_COMPUTE(k & 3);
  }
  #undef GP_COMPUTE

  #pragma unroll
  for (int m = 0; m < 2; ++m)
    #pragma unroll
    for (int n = 0; n < 4; ++n)
      #pragma unroll
      for (int r = 0; r < 4; ++r) {
        size_t idx = (size_t)(row0 + wrow + m * 16 + lq * 4 + r) * N
                   + (col0 + wcol + n * 16 + l15);
        C[idx] = acc[m][n][r] + R[idx];
      }
}

// ---------------- Deep-pipelined QKV GEMM + fused RoPE epilogue ----------------
__global__ __launch_bounds__(256) void gemm_qkv_kernel(const bf16* __restrict__ A,
    const bf16* __restrict__ Wcat, const float* __restrict__ tab,
    bf16* __restrict__ Qh, bf16* __restrict__ Kh, bf16* __restrict__ Vt) {
  __shared__ __align__(16) bf16 At[4][64 * 32];
  __shared__ __align__(16) bf16 Bt[4][128 * 32];
  const int K = DMODEL;
  int t = threadIdx.x, lane = t & 63, wave = t >> 6;
  int l15 = lane & 15, lq = lane >> 4;
  int wrow = (wave >> 1) * 32, wcol = (wave & 1) * 64;
  int row0 = blockIdx.y * 64, col0 = blockIdx.x * 128;
  const bf16* Ag  = A + (size_t)(row0 + (t >> 2)) * K + (t & 3) * 8;
  const bf16* Bg0 = Wcat + (size_t)(col0 + (t >> 2)) * K + (t & 3) * 8;
  const bf16* Bg1 = Bg0 + (size_t)64 * K;
  const int NS = K / 32;   // 24

  #pragma unroll
  for (int s = 0; s < 4; ++s) {
    int ks = s * 32;
    gl2lds16(Ag + ks,  At[s] + t * 8);
    gl2lds16(Bg0 + ks, Bt[s] + t * 8);
    gl2lds16(Bg1 + ks, Bt[s] + 2048 + t * 8);
  }

  f32x4 zero = {0.f, 0.f, 0.f, 0.f};
  f32x4 acc[2][4];
  #pragma unroll
  for (int m = 0; m < 2; ++m)
    #pragma unroll
    for (int n = 0; n < 4; ++n) acc[m][n] = zero;

  #define QK_COMPUTE(slot) do {                                              \
    const bf16* at = At[slot]; const bf16* bt = Bt[slot];                    \
    bf16x8 af[2], bfr[4];                                                    \
    _Pragma("unroll")                                                        \
    for (int m = 0; m < 2; ++m)                                              \
      af[m] = *(const bf16x8*)(at + (wrow + m * 16 + l15) * 32 + lq * 8);    \
    _Pragma("unroll")                                                        \
    for (int n = 0; n < 4; ++n)                                              \
      bfr[n] = *(const bf16x8*)(bt + (wcol + n * 16 + l15) * 32 + lq * 8);   \
    _Pragma("unroll")                                                        \
    for (int m = 0; m < 2; ++m)                                              \
      _Pragma("unroll")                                                      \
      for (int n = 0; n < 4; ++n)                                            \
        acc[m][n] = MFMA16(af[m], bfr[n], acc[m][n]);                        \
  } while (0)

  for (int k = 0; k < NS - 3; ++k) {
    WB(9);
    QK_COMPUTE(k & 3);
    BAR();
    if (k <= NS - 5) {
      int ks = (k + 4) * 32;
      gl2lds16(Ag + ks,  At[k & 3] + t * 8);
      gl2lds16(Bg0 + ks, Bt[k & 3] + t * 8);
      gl2lds16(Bg1 + ks, Bt[k & 3] + 2048 + t * 8);
    }
  }
  for (int k = NS - 3; k < NS; ++k) {
    WB(0);
    QK_COMPUTE(k & 3);
  }
  #undef QK_COMPUTE

  // ---- epilogue: RoPE (Q,K) / transpose-store (V) ----
  int b = row0 >> 11;
  int s0 = (row0 & 2047) + wrow + lq * 4;
  int colw = col0 + wcol;
  if (colw < 768) {
    int h = colw >> 6;
    f32x4 cv[2][2], sv[2][2];
    #pragma unroll
    for (int m = 0; m < 2; ++m)
      #pragma unroll
      for (int jh = 0; jh < 2; ++jh) {
        const float* cp = tab + (jh * 16 + l15) * 2048 + s0 + m * 16;
        cv[m][jh] = *(const f32x4*)cp;
        sv[m][jh] = *(const f32x4*)(cp + 65536);
      }
    #pragma unroll
    for (int m = 0; m < 2; ++m)
      #pragma unroll
      for (int n = 0; n < 4; ++n) {
        float sgn = (n < 2) ? -1.f : 1.f;
        #pragma unroll
        for (int r = 0; r < 4; ++r) {
          float c = cv[m][n & 1][r], si = sv[m][n & 1][r];
          float rp = (acc[m][n][r] * c + sgn * acc[m][n ^ 2][r] * si) * QSCALE;
          Qh[((size_t)(b * NH + h) * SEQ + s0 + m * 16 + r) * 64 + n * 16 + l15] = (bf16)rp;
        }
      }
  } else if (colw < 1024) {
    int kh = (colw - 768) >> 6;
    f32x4 cv[2][2], sv[2][2];
    #pragma unroll
    for (int m = 0; m < 2; ++m)
      #pragma unroll
      for (int jh = 0; jh < 2; ++jh) {
        const float* cp = tab + (jh * 16 + l15) * 2048 + s0 + m * 16;
        cv[m][jh] = *(const f32x4*)cp;
        sv[m][jh] = *(const f32x4*)(cp + 65536);
      }
    #pragma unroll
    for (int m = 0; m < 2; ++m)
      #pragma unroll
      for (int n = 0; n < 4; ++n) {
        float sgn = (n < 2) ? -1.f : 1.f;
        #pragma unroll
        for (int r = 0; r < 4; ++r) {
          float c = cv[m][n & 1][r], si = sv[m][n & 1][r];
          float rp = acc[m][n][r] * c + sgn * acc[m][n ^ 2][r] * si;
          Kh[((size_t)(b * NKV + kh) * SEQ + s0 + m * 16 + r) * 64 + n * 16 + l15] = (bf16)rp;
        }
      }
  } else {
    int vh = (colw - 1024) >> 6;
    #pragma unroll
    for (int m = 0; m < 2; ++m)
      #pragma unroll
      for (int n = 0; n < 4; ++n) {
        bf16x4 pv;
        #pragma unroll
        for (int r = 0; r < 4; ++r) pv[r] = (bf16)acc[m][n][r];
        *(bf16x4*)(Vt + ((size_t)(b * NKV + vh) * 64 + n * 16 + l15) * SEQ + s0 + m * 16) = pv;
      }
  }
}

// ---------------- Deep-pipelined gate/up GEMM + silu (L=4, wait vmcnt(12)) ----------------
__global__ __launch_bounds__(256) void gemm_gu_kernel(const bf16* __restrict__ A,
    const bf16* __restrict__ Wg, const bf16* __restrict__ Wu, bf16* __restrict__ H) {
  __shared__ __align__(16) bf16 At[4][128 * 32];   // 32KB
  __shared__ __align__(16) bf16 Bgt[4][64 * 32];   // 16KB
  __shared__ __align__(16) bf16 But[4][64 * 32];   // 16KB
  const int K = DMODEL;
  int t = threadIdx.x, lane = t & 63, wave = t >> 6;
  int l15 = lane & 15, lq = lane >> 4;
  int wrow = (wave >> 1) * 64, wcol = (wave & 1) * 32;
  int row0 = blockIdx.y * 128, col0 = blockIdx.x * 64;
  const bf16* Ag0 = A + (size_t)(row0 + (t >> 2)) * K + (t & 3) * 8;
  const bf16* Ag1 = Ag0 + (size_t)64 * K;
  const bf16* Gg  = Wg + (size_t)(col0 + (t >> 2)) * K + (t & 3) * 8;
  const bf16* Ug  = Wu + (size_t)(col0 + (t >> 2)) * K + (t & 3) * 8;
  const int NS = K / 32;   // 24

  #pragma unroll
  for (int s = 0; s < 4; ++s) {
    int ks = s * 32;
    gl2lds16(Ag0 + ks, At[s] + t * 8);
    gl2lds16(Ag1 + ks, At[s] + 2048 + t * 8);
    gl2lds16(Gg + ks,  Bgt[s] + t * 8);
    gl2lds16(Ug + ks,  But[s] + t * 8);
  }

  f32x4 zero = {0.f, 0.f, 0.f, 0.f};
  f32x4 ag[4][2], au[4][2];
  #pragma unroll
  for (int m = 0; m < 4; ++m)
    #pragma unroll
    for (int n = 0; n < 2; ++n) { ag[m][n] = zero; au[m][n] = zero; }

  #define GU_COMPUTE(slot) do {                                              \
    const bf16* at = At[slot];                                               \
    const bf16* bgt = Bgt[slot]; const bf16* but = But[slot];                \
    bf16x8 af[4], bg[2], bu[2];                                              \
    _Pragma("unroll")                                                        \
    for (int m = 0; m < 4; ++m)                                              \
      af[m] = *(const bf16x8*)(at + (wrow + m * 16 + l15) * 32 + lq * 8);    \
    _Pragma("unroll")                                                        \
    for (int n = 0; n < 2; ++n) {                                            \
      bg[n] = *(const bf16x8*)(bgt + (wcol + n * 16 + l15) * 32 + lq * 8);   \
      bu[n] = *(const bf16x8*)(but + (wcol + n * 16 + l15) * 32 + lq * 8);   \
    }                                                                        \
    _Pragma("unroll")                                                        \
    for (int m = 0; m < 4; ++m)                                              \
      _Pragma("unroll")                                                      \
      for (int n = 0; n < 2; ++n) {                                          \
        ag[m][n] = MFMA16(af[m], bg[n], ag[m][n]);                           \
        au[m][n] = MFMA16(af[m], bu[n], au[m][n]);                           \
      }                                                                      \
  } while (0)

  for (int k = 0; k < NS - 3; ++k) {
    WB(12);
    GU_COMPUTE(k & 3);
    BAR();
    if (k <= NS - 5) {
      int ks = (k + 4) * 32;
      gl2lds16(Ag0 + ks, At[k & 3] + t * 8);
      gl2lds16(Ag1 + ks, At[k & 3] + 2048 + t * 8);
      gl2lds16(Gg + ks,  Bgt[k & 3] + t * 8);
      gl2lds16(Ug + ks,  But[k & 3] + t * 8);
    }
  }
  for (int k = NS - 3; k < NS; ++k) {
    WB(0);
    GU_COMPUTE(k & 3);
  }
  #undef GU_COMPUTE

  #pragma unroll
  for (int m = 0; m < 4; ++m)
    #pragma unroll
    for (int n = 0; n < 2; ++n)
      #pragma unroll
      for (int r = 0; r < 4; ++r) {
        int row = row0 + wrow + m * 16 + lq * 4 + r;
        int col = col0 + wcol + n * 16 + l15;
        float g = ag[m][n][r], u = au[m][n][r];
        float sg = g / (1.f + __builtin_amdgcn_exp2f(-g * LOG2E));
        H[(size_t)row * FFDIM + col] = (bf16)(sg * u);
      }
}

// ---------------- Flash attention: S-transpose, fixed-max softmax, 2-slot K/V ring ----------
__global__ __launch_bounds__(256) void attn_kernel(const bf16* __restrict__ Qh,
    const bf16* __restrict__ Kh, const bf16* __restrict__ Vt, bf16* __restrict__ out) {
  __shared__ __align__(16) bf16 Kl0[2][64 * 32];
  __shared__ __align__(16) bf16 Kl1[2][64 * 32];
  __shared__ __align__(16) bf16 Vl0[2][64 * 32];
  __shared__ __align__(16) bf16 Vl1[2][64 * 32];
  __shared__ __align__(16) bf16 P[4][16 * 80];

  int idx = blockIdx.x;
  int qt = 31 - (idx / 24);                      // LPT: heaviest first
  int bh = idx % 24;
  int q0blk = qt * 64;
  int b = bh / NH, h = bh % NH;
  int kvh = h / NREP;
  int t = threadIdx.x;
  int lane = t & 63, wave = t >> 6;
  int l15 = lane & 15, lq = lane >> 4;
  int qw = q0blk + wave * 16;
  const bf16* Qb = Qh + (size_t)(b * NH + h) * SEQ * 64;
  const bf16* Kb = Kh + (size_t)(b * NKV + kvh) * SEQ * 64;
  const bf16* Vb = Vt + (size_t)(b * NKV + kvh) * 64 * SEQ;

  bf16x8 bq0 = *(const bf16x8*)(Qb + (size_t)(qw + l15) * 64 + lq * 8);
  bf16x8 bq1 = *(const bf16x8*)(Qb + (size_t)(qw + l15) * 64 + 32 + lq * 8);

  const bf16* Kg = Kb + (size_t)(t >> 2) * 64 + (t & 3) * 8;
  const bf16* Vg = Vb + (size_t)(t >> 2) * SEQ + (t & 3) * 8;
  bf16* Pw = P[wave];
  int Pwq = l15 * 80, lq8 = lq * 8, lq4 = lq * 4;
  const int NS = qt + 1;                         // 64-key steps

  #pragma unroll
  for (int s = 0; s < 2; ++s) {
    int ks = (s < NS ? s : NS - 1) * 64;
    gl2lds16(Kg + (size_t)ks * 64,      Kl0[s] + t * 8);
    gl2lds16(Kg + (size_t)ks * 64 + 32, Kl1[s] + t * 8);
    gl2lds16(Vg + ks,                   Vl0[s] + t * 8);
    gl2lds16(Vg + ks + 32,              Vl1[s] + t * 8);
  }

  f32x4 zero = {0.f, 0.f, 0.f, 0.f};
  f32x4 o[4];
  o[0] = zero; o[1] = zero; o[2] = zero; o[3] = zero;
  float l_r = 0.f;

  #define ATTN_STEP(kk, slot) do {                                           \
    int k0 = (kk) * 64;                                                      \
    const bf16* kl0 = Kl0[slot]; const bf16* kl1 = Kl1[slot];                \
    const bf16* vl0 = Vl0[slot]; const bf16* vl1 = Vl1[slot];                \
    f32x4 s[4];                                                              \
    _Pragma("unroll")                                                        \
    for (int c = 0; c < 4; ++c) {                                            \
      bf16x8 ak0 = *(const bf16x8*)(kl0 + (c * 16 + l15) * 32 + lq8);        \
      bf16x8 ak1 = *(const bf16x8*)(kl1 + (c * 16 + l15) * 32 + lq8);        \
      s[c] = zero;                                                           \
      s[c] = MFMA16(ak0, bq0, s[c]);                                         \
      s[c] = MFMA16(ak1, bq1, s[c]);                                         \
    }                                                                        \
    if (k0 + 63 > qw) {                                                      \
      int qmk = qw + l15 - k0 - lq4;                                         \
      _Pragma("unroll")                                                      \
      for (int c = 0; c < 4; ++c)                                            \
        _Pragma("unroll")                                                    \
        for (int r = 0; r < 4; ++r)                                          \
          if (c * 16 + r > qmk) s[c][r] = -INFINITY;                         \
    }                                                                        \
    _Pragma("unroll")                                                        \
    for (int c = 0; c < 4; ++c) {                                            \
      bf16x4 pe;                                                             \
      _Pragma("unroll")                                                      \
      for (int r = 0; r < 4; ++r) {                                          \
        float e = __builtin_amdgcn_exp2f(s[c][r]);                           \
        l_r += e;                                                            \
        pe[r] = (bf16)e;                                                     \
      }                                                                      \
      *(bf16x4*)(Pw + Pwq + c * 16 + lq4) = pe;                              \
    }                                                                        \
    bf16x8 bp0 = *(const bf16x8*)(Pw + Pwq + lq8);                           \
    bf16x8 bp1 = *(const bf16x8*)(Pw + Pwq + 32 + lq8);                      \
    _Pragma("unroll")                                                        \
    for (int n = 0; n < 4; ++n) {                                            \
      bf16x8 av0 = *(const bf16x8*)(vl0 + (n * 16 + l15) * 32 + lq8);        \
      bf16x8 av1 = *(const bf16x8*)(vl1 + (n * 16 + l15) * 32 + lq8);        \
      o[n] = MFMA16(av0, bp0, o[n]);                                         \
      o[n] = MFMA16(av1, bp1, o[n]);                                         \
    }                                                                        \
  } while (0)

  for (int k = 0; k < NS - 1; ++k) {
    WB(4);                        // stage k resident (1 newer stage = 4 loads in flight)
    ATTN_STEP(k, k & 1);
    BAR();
    if (k <= NS - 3) {
      int ks = (k + 2) * 64;
      gl2lds16(Kg + (size_t)ks * 64,      Kl0[k & 1] + t * 8);
      gl2lds16(Kg + (size_t)ks * 64 + 32, Kl1[k & 1] + t * 8);
      gl2lds16(Vg + ks,                   Vl0[k & 1] + t * 8);
      gl2lds16(Vg + ks + 32,              Vl1[k & 1] + t * 8);
    }
  }
  {
    WB(0);
    ATTN_STEP(NS - 1, (NS - 1) & 1);
  }
  #undef ATTN_STEP

  float lt = l_r;
  lt += __shfl_xor(lt, 16, 64);
  lt += __shfl_xor(lt, 32, 64);
  float inv = 1.f / lt;
  int q = qw + l15;
  bf16* orow = out + (size_t)(b * SEQ + q) * DMODEL + h * 64;
  #pragma unroll
  for (int n = 0; n < 4; ++n) {
    bf16x4 po;
    #pragma unroll
    for (int r = 0; r < 4; ++r) po[r] = (bf16)(o[n][r] * inv);
    *(bf16x4*)(orow + n * 16 + lq4) = po;
  }
}

extern "C" void kernel_launch(void* const* d_in, const int* in_sizes, int n_in,
                              void* d_out, int out_size, void* d_ws, size_t ws_size,
                              hipStream_t stream) {
  const float* x     = (const float*)d_in[0];
  const float* Wq    = (const float*)d_in[1];
  const float* Wk    = (const float*)d_in[2];
  const float* Wv    = (const float*)d_in[3];
  const float* Wo    = (const float*)d_in[4];
  const float* Wgate = (const float*)d_in[5];
  const float* Wup   = (const float*)d_in[6];
  const float* Wdown = (const float*)d_in[7];
  const float* g1    = (const float*)d_in[8];
  const float* g2    = (const float*)d_in[9];
  float* out = (float*)d_out;

  char* ws = (char*)d_ws;
  size_t off = 0;
  auto alloc = [&](size_t bytes) { size_t o = off; off += (bytes + 255) & ~(size_t)255; return o; };
  size_t o_tab  = alloc((size_t)2 * 32 * 2048 * 4);          // 512KB cos/sin
  size_t o_x1   = alloc((size_t)4096 * 768 * 4);
  size_t o_xn   = alloc((size_t)4096 * 768 * 2);
  size_t o_Qh   = alloc((size_t)2 * 12 * 2048 * 64 * 2);
  size_t o_Kh   = alloc((size_t)2 * 4 * 2048 * 64 * 2);
  size_t o_Vt   = alloc((size_t)2 * 4 * 64 * 2048 * 2);
  size_t o_ao   = alloc((size_t)4096 * 768 * 2);
  size_t o_H    = alloc((size_t)4096 * 2048 * 2);
  size_t o_Wcat = alloc((size_t)1280 * 768 * 2);
  size_t o_Wo   = alloc((size_t)768 * 768 * 2);
  size_t o_Wgu  = alloc((size_t)4096 * 768 * 2);
  size_t o_Wdn  = alloc((size_t)768 * 2048 * 2);
  if (ws_size < off) return;

  float* tab  = (float*)(ws + o_tab);
  float* fx1  = (float*)(ws + o_x1);
  bf16* bxn   = (bf16*)(ws + o_xn);
  bf16* bQh   = (bf16*)(ws + o_Qh);
  bf16* bKh   = (bf16*)(ws + o_Kh);
  bf16* bVt   = (bf16*)(ws + o_Vt);
  bf16* bao   = (bf16*)(ws + o_ao);
  bf16* bH    = (bf16*)(ws + o_H);
  bf16* bWcat = (bf16*)(ws + o_Wcat);
  bf16* bWo   = (bf16*)(ws + o_Wo);
  bf16* bWgu  = (bf16*)(ws + o_Wgu);
  bf16* bWdn  = (bf16*)(ws + o_Wdn);

  rope_tab_kernel<<<256, 256, 0, stream>>>(tab);

  Cvt7 c;
  c.s[0] = Wq;    c.d[0] = bWcat;              c.n[0] = 768 * 768;
  c.s[1] = Wk;    c.d[1] = bWcat + 768 * 768;  c.n[1] = 256 * 768;
  c.s[2] = Wv;    c.d[2] = bWcat + 1024 * 768; c.n[2] = 256 * 768;
  c.s[3] = Wo;    c.d[3] = bWo;                c.n[3] = 768 * 768;
  c.s[4] = Wgate; c.d[4] = bWgu;               c.n[4] = 2048 * 768;
  c.s[5] = Wup;   c.d[5] = bWgu + 2048 * 768;  c.n[5] = 2048 * 768;
  c.s[6] = Wdown; c.d[6] = bWdn;               c.n[6] = 768 * 2048;
  cvt_all_kernel<<<dim3(256, 7), 256, 0, stream>>>(c);

  // Attention sublayer
  rmsnorm_kernel<<<4096, 192, 0, stream>>>(x, g1, bxn);
  gemm_qkv_kernel<<<dim3(10, 64), 256, 0, stream>>>(bxn, bWcat, tab, bQh, bKh, bVt);
  attn_kernel<<<dim3(768), 256, 0, stream>>>(bQh, bKh, bVt, bao);
  gemm_pipe_kernel<<<dim3(6, 64), 256, 0, stream>>>(bao, bWo, fx1, x, 768, 768);

  // FFN sublayer
  rmsnorm_kernel<<<4096, 192, 0, stream>>>(fx1, g2, bxn);
  gemm_gu_kernel<<<dim3(32, 32), 256, 0, stream>>>(bxn, bWgu, bWgu + 2048 * 768, bH);
  gemm_pipe_kernel<<<dim3(6, 64), 256, 0, stream>>>(bH, bWdn, out, fx1, 768, 2048);
}

// Round 10
// 254.994 us; speedup vs baseline: 1.5634x; 1.0235x over previous
//
#include <hip/hip_runtime.h>
#include <hip/hip_bf16.h>
#include <math.h>

typedef __bf16 bf16;
typedef __attribute__((ext_vector_type(8))) __bf16 bf16x8;
typedef __attribute__((ext_vector_type(4))) __bf16 bf16x4;
typedef __attribute__((ext_vector_type(4))) float f32x4;

#define MFMA16(a,b,c) __builtin_amdgcn_mfma_f32_16x16x32_bf16(a,b,c,0,0,0)

// Problem constants
#define BATCH 2
#define SEQ   2048
#define DMODEL 768
#define NH    12
#define NKV   4
#define NREP  3
#define HD    64
#define FFDIM 2048
#define ROWS  (BATCH*SEQ)   // 4096

#define QSCALE 0.18033688011112042f
#define LOG2E  1.4426950408889634f

// Partial-drain barrier: wait until <=N vector-mem ops outstanding, then barrier.
// AITER/hipBLASLt pattern — prefetched gl2lds stages stay in flight across the
// barrier (a plain __syncthreads would emit vmcnt(0) and drain them).
#define WB(N) asm volatile("s_waitcnt vmcnt(" #N ")\n\ts_barrier" ::: "memory")
#define BAR() asm volatile("s_barrier" ::: "memory")

__device__ __forceinline__ void gl2lds16(const bf16* g, bf16* l) {
  __builtin_amdgcn_global_load_lds(
      (const __attribute__((address_space(1))) void*)g,
      (__attribute__((address_space(3))) void*)l, 16, 0, 0);
}

// ---------------- fused fp32 -> bf16 convert (7 weight segments) ----------------
struct Cvt7 { const float* s[7]; bf16* d[7]; int n[7]; };
__global__ __launch_bounds__(256) void cvt_all_kernel(Cvt7 c) {
  int seg = blockIdx.y;
  const float* __restrict__ src = c.s[seg];
  bf16* __restrict__ dst = c.d[seg];
  int n = c.n[seg];
  int stride = gridDim.x * 256;
  for (int i = blockIdx.x * 256 + threadIdx.x; i < n; i += stride)
    dst[i] = (bf16)src[i];
}

// ---------------- RoPE cos/sin table ----------------
__global__ __launch_bounds__(256) void rope_tab_kernel(float* __restrict__ tab) {
  int id = blockIdx.x * 256 + threadIdx.x;    // 65536 = 32 j * 2048 s
  int j = id >> 11, s = id & 2047;
  float inv = expf(-(float)j * (9.210340371976184f / 32.0f));
  float ang = (float)s * inv;
  tab[id] = cosf(ang);
  tab[65536 + id] = sinf(ang);
}

// ---------------- RMSNorm (vectorized f32x4, 192 threads) ----------------
__global__ __launch_bounds__(192) void rmsnorm_kernel(const float* __restrict__ x,
    const float* __restrict__ g, bf16* __restrict__ out) {
  int row = blockIdx.x;
  const float* xr = x + (size_t)row * DMODEL;
  int t = threadIdx.x;
  f32x4 v = *(const f32x4*)(xr + t * 4);
  float ss = v[0] * v[0] + v[1] * v[1] + v[2] * v[2] + v[3] * v[3];
  #pragma unroll
  for (int off = 32; off; off >>= 1) ss += __shfl_xor(ss, off, 64);
  __shared__ float red[3];
  if ((t & 63) == 0) red[t >> 6] = ss;
  __syncthreads();
  float total = red[0] + red[1] + red[2];
  float norm = sqrtf(total) * 0.03608439182435161f;  // 768^-0.5
  float sc = 1.0f / (norm + 1e-6f);
  f32x4 gv = *(const f32x4*)(g + t * 4);
  bf16x4 o;
  #pragma unroll
  for (int i = 0; i < 4; ++i) o[i] = (bf16)(gv[i] * v[i] * sc);
  *(bf16x4*)(out + (size_t)row * DMODEL + t * 4) = o;
}

// ---------------- Deep-pipelined GEMM 64x64: C(fp32) = A@B^T + R ----------------
// Grid 12x64 = 768 blocks = 3/CU. Ring-4 LDS (32KB), 2 loads/thread/stage, WB(6).
// Wave tile 32x32 (2x2 waves), 8 MFMA/stage/wave.
__global__ __launch_bounds__(256) void gemm_pipe64_kernel(const bf16* __restrict__ A,
    const bf16* __restrict__ B, float* __restrict__ C, const float* __restrict__ R,
    int N, int K) {
  __shared__ __align__(16) bf16 At[4][64 * 32];    // 16KB
  __shared__ __align__(16) bf16 Bt[4][64 * 32];    // 16KB
  int t = threadIdx.x, lane = t & 63, wave = t >> 6;
  int l15 = lane & 15, lq = lane >> 4;
  int wrow = (wave >> 1) * 32, wcol = (wave & 1) * 32;
  int row0 = blockIdx.y * 64, col0 = blockIdx.x * 64;
  const bf16* Ag = A + (size_t)(row0 + (t >> 2)) * K + (t & 3) * 8;
  const bf16* Bg = B + (size_t)(col0 + (t >> 2)) * K + (t & 3) * 8;
  const int NS = K / 32;

  #pragma unroll
  for (int s = 0; s < 4; ++s) {
    int ks = s * 32;
    gl2lds16(Ag + ks, At[s] + t * 8);
    gl2lds16(Bg + ks, Bt[s] + t * 8);
  }

  f32x4 zero = {0.f, 0.f, 0.f, 0.f};
  f32x4 acc[2][2];
  #pragma unroll
  for (int m = 0; m < 2; ++m)
    #pragma unroll
    for (int n = 0; n < 2; ++n) acc[m][n] = zero;

  #define GP_COMPUTE(slot) do {                                              \
    const bf16* at = At[slot]; const bf16* bt = Bt[slot];                    \
    bf16x8 af[2], bfr[2];                                                    \
    _Pragma("unroll")                                                        \
    for (int m = 0; m < 2; ++m)                                              \
      af[m] = *(const bf16x8*)(at + (wrow + m * 16 + l15) * 32 + lq * 8);    \
    _Pragma("unroll")                                                        \
    for (int n = 0; n < 2; ++n)                                              \
      bfr[n] = *(const bf16x8*)(bt + (wcol + n * 16 + l15) * 32 + lq * 8);   \
    _Pragma("unroll")                                                        \
    for (int m = 0; m < 2; ++m)                                              \
      _Pragma("unroll")                                                      \
      for (int n = 0; n < 2; ++n)                                            \
        acc[m][n] = MFMA16(af[m], bfr[n], acc[m][n]);                        \
  } while (0)

  for (int k = 0; k < NS - 3; ++k) {
    WB(6);                        // stage k resident for all waves
    GP_COMPUTE(k & 3);
    BAR();                        // all waves done reading slot k&3
    if (k <= NS - 5) {
      int ks = (k + 4) * 32;
      gl2lds16(Ag + ks, At[k & 3] + t * 8);
      gl2lds16(Bg + ks, Bt[k & 3] + t * 8);
    }
  }
  for (int k = NS - 3; k < NS; ++k) {
    WB(0);                        // conservative tail drain
    GP_COMPUTE(k & 3);
  }
  #undef GP_COMPUTE

  #pragma unroll
  for (int m = 0; m < 2; ++m)
    #pragma unroll
    for (int n = 0; n < 2; ++n)
      #pragma unroll
      for (int r = 0; r < 4; ++r) {
        size_t idx = (size_t)(row0 + wrow + m * 16 + lq * 4 + r) * N
                   + (col0 + wcol + n * 16 + l15);
        C[idx] = acc[m][n][r] + R[idx];
      }
}

// ---------------- Deep-pipelined QKV GEMM + fused RoPE epilogue ----------------
__global__ __launch_bounds__(256) void gemm_qkv_kernel(const bf16* __restrict__ A,
    const bf16* __restrict__ Wcat, const float* __restrict__ tab,
    bf16* __restrict__ Qh, bf16* __restrict__ Kh, bf16* __restrict__ Vt) {
  __shared__ __align__(16) bf16 At[4][64 * 32];
  __shared__ __align__(16) bf16 Bt[4][128 * 32];
  const int K = DMODEL;
  int t = threadIdx.x, lane = t & 63, wave = t >> 6;
  int l15 = lane & 15, lq = lane >> 4;
  int wrow = (wave >> 1) * 32, wcol = (wave & 1) * 64;
  int row0 = blockIdx.y * 64, col0 = blockIdx.x * 128;
  const bf16* Ag  = A + (size_t)(row0 + (t >> 2)) * K + (t & 3) * 8;
  const bf16* Bg0 = Wcat + (size_t)(col0 + (t >> 2)) * K + (t & 3) * 8;
  const bf16* Bg1 = Bg0 + (size_t)64 * K;
  const int NS = K / 32;   // 24

  #pragma unroll
  for (int s = 0; s < 4; ++s) {
    int ks = s * 32;
    gl2lds16(Ag + ks,  At[s] + t * 8);
    gl2lds16(Bg0 + ks, Bt[s] + t * 8);
    gl2lds16(Bg1 + ks, Bt[s] + 2048 + t * 8);
  }

  f32x4 zero = {0.f, 0.f, 0.f, 0.f};
  f32x4 acc[2][4];
  #pragma unroll
  for (int m = 0; m < 2; ++m)
    #pragma unroll
    for (int n = 0; n < 4; ++n) acc[m][n] = zero;

  #define QK_COMPUTE(slot) do {                                              \
    const bf16* at = At[slot]; const bf16* bt = Bt[slot];                    \
    bf16x8 af[2], bfr[4];                                                    \
    _Pragma("unroll")                                                        \
    for (int m = 0; m < 2; ++m)                                              \
      af[m] = *(const bf16x8*)(at + (wrow + m * 16 + l15) * 32 + lq * 8);    \
    _Pragma("unroll")                                                        \
    for (int n = 0; n < 4; ++n)                                              \
      bfr[n] = *(const bf16x8*)(bt + (wcol + n * 16 + l15) * 32 + lq * 8);   \
    _Pragma("unroll")                                                        \
    for (int m = 0; m < 2; ++m)                                              \
      _Pragma("unroll")                                                      \
      for (int n = 0; n < 4; ++n)                                            \
        acc[m][n] = MFMA16(af[m], bfr[n], acc[m][n]);                        \
  } while (0)

  for (int k = 0; k < NS - 3; ++k) {
    WB(9);
    QK_COMPUTE(k & 3);
    BAR();
    if (k <= NS - 5) {
      int ks = (k + 4) * 32;
      gl2lds16(Ag + ks,  At[k & 3] + t * 8);
      gl2lds16(Bg0 + ks, Bt[k & 3] + t * 8);
      gl2lds16(Bg1 + ks, Bt[k & 3] + 2048 + t * 8);
    }
  }
  for (int k = NS - 3; k < NS; ++k) {
    WB(0);
    QK_COMPUTE(k & 3);
  }
  #undef QK_COMPUTE

  // ---- epilogue: RoPE (Q,K) / transpose-store (V) ----
  int b = row0 >> 11;
  int s0 = (row0 & 2047) + wrow + lq * 4;
  int colw = col0 + wcol;
  if (colw < 768) {
    int h = colw >> 6;
    f32x4 cv[2][2], sv[2][2];
    #pragma unroll
    for (int m = 0; m < 2; ++m)
      #pragma unroll
      for (int jh = 0; jh < 2; ++jh) {
        const float* cp = tab + (jh * 16 + l15) * 2048 + s0 + m * 16;
        cv[m][jh] = *(const f32x4*)cp;
        sv[m][jh] = *(const f32x4*)(cp + 65536);
      }
    #pragma unroll
    for (int m = 0; m < 2; ++m)
      #pragma unroll
      for (int n = 0; n < 4; ++n) {
        float sgn = (n < 2) ? -1.f : 1.f;
        #pragma unroll
        for (int r = 0; r < 4; ++r) {
          float c = cv[m][n & 1][r], si = sv[m][n & 1][r];
          float rp = (acc[m][n][r] * c + sgn * acc[m][n ^ 2][r] * si) * QSCALE;
          Qh[((size_t)(b * NH + h) * SEQ + s0 + m * 16 + r) * 64 + n * 16 + l15] = (bf16)rp;
        }
      }
  } else if (colw < 1024) {
    int kh = (colw - 768) >> 6;
    f32x4 cv[2][2], sv[2][2];
    #pragma unroll
    for (int m = 0; m < 2; ++m)
      #pragma unroll
      for (int jh = 0; jh < 2; ++jh) {
        const float* cp = tab + (jh * 16 + l15) * 2048 + s0 + m * 16;
        cv[m][jh] = *(const f32x4*)cp;
        sv[m][jh] = *(const f32x4*)(cp + 65536);
      }
    #pragma unroll
    for (int m = 0; m < 2; ++m)
      #pragma unroll
      for (int n = 0; n < 4; ++n) {
        float sgn = (n < 2) ? -1.f : 1.f;
        #pragma unroll
        for (int r = 0; r < 4; ++r) {
          float c = cv[m][n & 1][r], si = sv[m][n & 1][r];
          float rp = acc[m][n][r] * c + sgn * acc[m][n ^ 2][r] * si;
          Kh[((size_t)(b * NKV + kh) * SEQ + s0 + m * 16 + r) * 64 + n * 16 + l15] = (bf16)rp;
        }
      }
  } else {
    int vh = (colw - 1024) >> 6;
    #pragma unroll
    for (int m = 0; m < 2; ++m)
      #pragma unroll
      for (int n = 0; n < 4; ++n) {
        bf16x4 pv;
        #pragma unroll
        for (int r = 0; r < 4; ++r) pv[r] = (bf16)acc[m][n][r];
        *(bf16x4*)(Vt + ((size_t)(b * NKV + vh) * 64 + n * 16 + l15) * SEQ + s0 + m * 16) = pv;
      }
  }
}

// ---------------- Deep-pipelined gate/up GEMM + silu (ring-3, 48KB LDS) ----------------
__global__ __launch_bounds__(256) void gemm_gu_kernel(const bf16* __restrict__ A,
    const bf16* __restrict__ Wg, const bf16* __restrict__ Wu, bf16* __restrict__ H) {
  __shared__ __align__(16) bf16 At[3][128 * 32];   // 24KB
  __shared__ __align__(16) bf16 Bgt[3][64 * 32];   // 12KB
  __shared__ __align__(16) bf16 But[3][64 * 32];   // 12KB
  const int K = DMODEL;
  int t = threadIdx.x, lane = t & 63, wave = t >> 6;
  int l15 = lane & 15, lq = lane >> 4;
  int wrow = (wave >> 1) * 64, wcol = (wave & 1) * 32;
  int row0 = blockIdx.y * 128, col0 = blockIdx.x * 64;
  const bf16* Ag0 = A + (size_t)(row0 + (t >> 2)) * K + (t & 3) * 8;
  const bf16* Ag1 = Ag0 + (size_t)64 * K;
  const bf16* Gg  = Wg + (size_t)(col0 + (t >> 2)) * K + (t & 3) * 8;
  const bf16* Ug  = Wu + (size_t)(col0 + (t >> 2)) * K + (t & 3) * 8;
  const int NS = K / 32;   // 24

  #pragma unroll
  for (int s = 0; s < 3; ++s) {
    int ks = s * 32;
    gl2lds16(Ag0 + ks, At[s] + t * 8);
    gl2lds16(Ag1 + ks, At[s] + 2048 + t * 8);
    gl2lds16(Gg + ks,  Bgt[s] + t * 8);
    gl2lds16(Ug + ks,  But[s] + t * 8);
  }

  f32x4 zero = {0.f, 0.f, 0.f, 0.f};
  f32x4 ag[4][2], au[4][2];
  #pragma unroll
  for (int m = 0; m < 4; ++m)
    #pragma unroll
    for (int n = 0; n < 2; ++n) { ag[m][n] = zero; au[m][n] = zero; }

  #define GU_COMPUTE(slot) do {                                              \
    const bf16* at = At[slot];                                               \
    const bf16* bgt = Bgt[slot]; const bf16* but = But[slot];                \
    bf16x8 af[4], bg[2], bu[2];                                              \
    _Pragma("unroll")                                                        \
    for (int m = 0; m < 4; ++m)                                              \
      af[m] = *(const bf16x8*)(at + (wrow + m * 16 + l15) * 32 + lq * 8);    \
    _Pragma("unroll")                                                        \
    for (int n = 0; n < 2; ++n) {                                            \
      bg[n] = *(const bf16x8*)(bgt + (wcol + n * 16 + l15) * 32 + lq * 8);   \
      bu[n] = *(const bf16x8*)(but + (wcol + n * 16 + l15) * 32 + lq * 8);   \
    }                                                                        \
    _Pragma("unroll")                                                        \
    for (int m = 0; m < 4; ++m)                                              \
      _Pragma("unroll")                                                      \
      for (int n = 0; n < 2; ++n) {                                          \
        ag[m][n] = MFMA16(af[m], bg[n], ag[m][n]);                           \
        au[m][n] = MFMA16(af[m], bu[n], au[m][n]);                           \
      }                                                                      \
  } while (0)

  int slot = 0;
  for (int k = 0; k < NS - 2; ++k) {
    WB(8);                        // stage k resident (2 newer stages x 4 loads)
    GU_COMPUTE(slot);
    BAR();
    if (k <= NS - 4) {
      int ks = (k + 3) * 32;
      gl2lds16(Ag0 + ks, At[slot] + t * 8);
      gl2lds16(Ag1 + ks, At[slot] + 2048 + t * 8);
      gl2lds16(Gg + ks,  Bgt[slot] + t * 8);
      gl2lds16(Ug + ks,  But[slot] + t * 8);
    }
    slot = (slot == 2) ? 0 : slot + 1;
  }
  for (int k = NS - 2; k < NS; ++k) {
    WB(0);
    GU_COMPUTE(slot);
    slot = (slot == 2) ? 0 : slot + 1;
  }
  #undef GU_COMPUTE

  #pragma unroll
  for (int m = 0; m < 4; ++m)
    #pragma unroll
    for (int n = 0; n < 2; ++n)
      #pragma unroll
      for (int r = 0; r < 4; ++r) {
        int row = row0 + wrow + m * 16 + lq * 4 + r;
        int col = col0 + wcol + n * 16 + l15;
        float g = ag[m][n][r], u = au[m][n][r];
        float sg = g / (1.f + __builtin_amdgcn_exp2f(-g * LOG2E));
        H[(size_t)row * FFDIM + col] = (bf16)(sg * u);
      }
}

// ---------------- Flash attention: S-transpose, fixed-max softmax, 2-slot K/V ring ----------
__global__ __launch_bounds__(256) void attn_kernel(const bf16* __restrict__ Qh,
    const bf16* __restrict__ Kh, const bf16* __restrict__ Vt, bf16* __restrict__ out) {
  __shared__ __align__(16) bf16 Kl0[2][64 * 32];
  __shared__ __align__(16) bf16 Kl1[2][64 * 32];
  __shared__ __align__(16) bf16 Vl0[2][64 * 32];
  __shared__ __align__(16) bf16 Vl1[2][64 * 32];
  __shared__ __align__(16) bf16 P[4][16 * 80];

  int idx = blockIdx.x;
  int qt = 31 - (idx / 24);                      // LPT: heaviest first
  int bh = idx % 24;
  int q0blk = qt * 64;
  int b = bh / NH, h = bh % NH;
  int kvh = h / NREP;
  int t = threadIdx.x;
  int lane = t & 63, wave = t >> 6;
  int l15 = lane & 15, lq = lane >> 4;
  int qw = q0blk + wave * 16;
  const bf16* Qb = Qh + (size_t)(b * NH + h) * SEQ * 64;
  const bf16* Kb = Kh + (size_t)(b * NKV + kvh) * SEQ * 64;
  const bf16* Vb = Vt + (size_t)(b * NKV + kvh) * 64 * SEQ;

  bf16x8 bq0 = *(const bf16x8*)(Qb + (size_t)(qw + l15) * 64 + lq * 8);
  bf16x8 bq1 = *(const bf16x8*)(Qb + (size_t)(qw + l15) * 64 + 32 + lq * 8);

  const bf16* Kg = Kb + (size_t)(t >> 2) * 64 + (t & 3) * 8;
  const bf16* Vg = Vb + (size_t)(t >> 2) * SEQ + (t & 3) * 8;
  bf16* Pw = P[wave];
  int Pwq = l15 * 80, lq8 = lq * 8, lq4 = lq * 4;
  const int NS = qt + 1;                         // 64-key steps

  #pragma unroll
  for (int s = 0; s < 2; ++s) {
    int ks = (s < NS ? s : NS - 1) * 64;
    gl2lds16(Kg + (size_t)ks * 64,      Kl0[s] + t * 8);
    gl2lds16(Kg + (size_t)ks * 64 + 32, Kl1[s] + t * 8);
    gl2lds16(Vg + ks,                   Vl0[s] + t * 8);
    gl2lds16(Vg + ks + 32,              Vl1[s] + t * 8);
  }

  f32x4 zero = {0.f, 0.f, 0.f, 0.f};
  f32x4 o[4];
  o[0] = zero; o[1] = zero; o[2] = zero; o[3] = zero;
  float l_r = 0.f;

  #define ATTN_STEP(kk, slot) do {                                           \
    int k0 = (kk) * 64;                                                      \
    const bf16* kl0 = Kl0[slot]; const bf16* kl1 = Kl1[slot];                \
    const bf16* vl0 = Vl0[slot]; const bf16* vl1 = Vl1[slot];                \
    f32x4 s[4];                                                              \
    _Pragma("unroll")                                                        \
    for (int c = 0; c < 4; ++c) {                                            \
      bf16x8 ak0 = *(const bf16x8*)(kl0 + (c * 16 + l15) * 32 + lq8);        \
      bf16x8 ak1 = *(const bf16x8*)(kl1 + (c * 16 + l15) * 32 + lq8);        \
      s[c] = zero;                                                           \
      s[c] = MFMA16(ak0, bq0, s[c]);                                         \
      s[c] = MFMA16(ak1, bq1, s[c]);                                         \
    }                                                                        \
    if (k0 + 63 > qw) {                                                      \
      int qmk = qw + l15 - k0 - lq4;                                         \
      _Pragma("unroll")                                                      \
      for (int c = 0; c < 4; ++c)                                            \
        _Pragma("unroll")                                                    \
        for (int r = 0; r < 4; ++r)                                          \
          if (c * 16 + r > qmk) s[c][r] = -INFINITY;                         \
    }                                                                        \
    _Pragma("unroll")                                                        \
    for (int c = 0; c < 4; ++c) {                                            \
      bf16x4 pe;                                                             \
      _Pragma("unroll")                                                      \
      for (int r = 0; r < 4; ++r) {                                          \
        float e = __builtin_amdgcn_exp2f(s[c][r]);                           \
        l_r += e;                                                            \
        pe[r] = (bf16)e;                                                     \
      }                                                                      \
      *(bf16x4*)(Pw + Pwq + c * 16 + lq4) = pe;                              \
    }                                                                        \
    bf16x8 bp0 = *(const bf16x8*)(Pw + Pwq + lq8);                           \
    bf16x8 bp1 = *(const bf16x8*)(Pw + Pwq + 32 + lq8);                      \
    _Pragma("unroll")                                                        \
    for (int n = 0; n < 4; ++n) {                                            \
      bf16x8 av0 = *(const bf16x8*)(vl0 + (n * 16 + l15) * 32 + lq8);        \
      bf16x8 av1 = *(const bf16x8*)(vl1 + (n * 16 + l15) * 32 + lq8);        \
      o[n] = MFMA16(av0, bp0, o[n]);                                         \
      o[n] = MFMA16(av1, bp1, o[n]);                                         \
    }                                                                        \
  } while (0)

  for (int k = 0; k < NS - 1; ++k) {
    WB(4);                        // stage k resident (1 newer stage = 4 loads in flight)
    ATTN_STEP(k, k & 1);
    BAR();
    if (k <= NS - 3) {
      int ks = (k + 2) * 64;
      gl2lds16(Kg + (size_t)ks * 64,      Kl0[k & 1] + t * 8);
      gl2lds16(Kg + (size_t)ks * 64 + 32, Kl1[k & 1] + t * 8);
      gl2lds16(Vg + ks,                   Vl0[k & 1] + t * 8);
      gl2lds16(Vg + ks + 32,              Vl1[k & 1] + t * 8);
    }
  }
  {
    WB(0);
    ATTN_STEP(NS - 1, (NS - 1) & 1);
  }
  #undef ATTN_STEP

  float lt = l_r;
  lt += __shfl_xor(lt, 16, 64);
  lt += __shfl_xor(lt, 32, 64);
  float inv = 1.f / lt;
  int q = qw + l15;
  bf16* orow = out + (size_t)(b * SEQ + q) * DMODEL + h * 64;
  #pragma unroll
  for (int n = 0; n < 4; ++n) {
    bf16x4 po;
    #pragma unroll
    for (int r = 0; r < 4; ++r) po[r] = (bf16)(o[n][r] * inv);
    *(bf16x4*)(orow + n * 16 + lq4) = po;
  }
}

extern "C" void kernel_launch(void* const* d_in, const int* in_sizes, int n_in,
                              void* d_out, int out_size, void* d_ws, size_t ws_size,
                              hipStream_t stream) {
  const float* x     = (const float*)d_in[0];
  const float* Wq    = (const float*)d_in[1];
  const float* Wk    = (const float*)d_in[2];
  const float* Wv    = (const float*)d_in[3];
  const float* Wo    = (const float*)d_in[4];
  const float* Wgate = (const float*)d_in[5];
  const float* Wup   = (const float*)d_in[6];
  const float* Wdown = (const float*)d_in[7];
  const float* g1    = (const float*)d_in[8];
  const float* g2    = (const float*)d_in[9];
  float* out = (float*)d_out;

  char* ws = (char*)d_ws;
  size_t off = 0;
  auto alloc = [&](size_t bytes) { size_t o = off; off += (bytes + 255) & ~(size_t)255; return o; };
  size_t o_tab  = alloc((size_t)2 * 32 * 2048 * 4);          // 512KB cos/sin
  size_t o_x1   = alloc((size_t)4096 * 768 * 4);
  size_t o_xn   = alloc((size_t)4096 * 768 * 2);
  size_t o_Qh   = alloc((size_t)2 * 12 * 2048 * 64 * 2);
  size_t o_Kh   = alloc((size_t)2 * 4 * 2048 * 64 * 2);
  size_t o_Vt   = alloc((size_t)2 * 4 * 64 * 2048 * 2);
  size_t o_ao   = alloc((size_t)4096 * 768 * 2);
  size_t o_H    = alloc((size_t)4096 * 2048 * 2);
  size_t o_Wcat = alloc((size_t)1280 * 768 * 2);
  size_t o_Wo   = alloc((size_t)768 * 768 * 2);
  size_t o_Wgu  = alloc((size_t)4096 * 768 * 2);
  size_t o_Wdn  = alloc((size_t)768 * 2048 * 2);
  if (ws_size < off) return;

  float* tab  = (float*)(ws + o_tab);
  float* fx1  = (float*)(ws + o_x1);
  bf16* bxn   = (bf16*)(ws + o_xn);
  bf16* bQh   = (bf16*)(ws + o_Qh);
  bf16* bKh   = (bf16*)(ws + o_Kh);
  bf16* bVt   = (bf16*)(ws + o_Vt);
  bf16* bao   = (bf16*)(ws + o_ao);
  bf16* bH    = (bf16*)(ws + o_H);
  bf16* bWcat = (bf16*)(ws + o_Wcat);
  bf16* bWo   = (bf16*)(ws + o_Wo);
  bf16* bWgu  = (bf16*)(ws + o_Wgu);
  bf16* bWdn  = (bf16*)(ws + o_Wdn);

  rope_tab_kernel<<<256, 256, 0, stream>>>(tab);

  Cvt7 c;
  c.s[0] = Wq;    c.d[0] = bWcat;              c.n[0] = 768 * 768;
  c.s[1] = Wk;    c.d[1] = bWcat + 768 * 768;  c.n[1] = 256 * 768;
  c.s[2] = Wv;    c.d[2] = bWcat + 1024 * 768; c.n[2] = 256 * 768;
  c.s[3] = Wo;    c.d[3] = bWo;                c.n[3] = 768 * 768;
  c.s[4] = Wgate; c.d[4] = bWgu;               c.n[4] = 2048 * 768;
  c.s[5] = Wup;   c.d[5] = bWgu + 2048 * 768;  c.n[5] = 2048 * 768;
  c.s[6] = Wdown; c.d[6] = bWdn;               c.n[6] = 768 * 2048;
  cvt_all_kernel<<<dim3(256, 7), 256, 0, stream>>>(c);

  // Attention sublayer
  rmsnorm_kernel<<<4096, 192, 0, stream>>>(x, g1, bxn);
  gemm_qkv_kernel<<<dim3(10, 64), 256, 0, stream>>>(bxn, bWcat, tab, bQh, bKh, bVt);
  attn_kernel<<<dim3(768), 256, 0, stream>>>(bQh, bKh, bVt, bao);
  gemm_pipe64_kernel<<<dim3(12, 64), 256, 0, stream>>>(bao, bWo, fx1, x, 768, 768);

  // FFN sublayer
  rmsnorm_kernel<<<4096, 192, 0, stream>>>(fx1, g2, bxn);
  gemm_gu_kernel<<<dim3(32, 32), 256, 0, stream>>>(bxn, bWgu, bWgu + 2048 * 768, bH);
  gemm_pipe64_kernel<<<dim3(12, 64), 256, 0, stream>>>(bH, bWdn, out, fx1, 768, 2048);
}